// Round 5
// baseline (529.617 us; speedup 1.0000x reference)
//
#include <hip/hip_runtime.h>

#define NE 50000      // N_ENT
#define NR 200        // N_REL
#define EF 300000     // E_FULL
#define EB 80000      // E_BATCH
#define NEG 0.2f

typedef unsigned short u16;
typedef unsigned int u32;
typedef u16 u16x8 __attribute__((ext_vector_type(8)));
typedef __bf16 bf16x8 __attribute__((ext_vector_type(8)));
typedef float f32x4 __attribute__((ext_vector_type(4)));

__device__ __forceinline__ float lrelu(float x){ return x >= 0.f ? x : NEG*x; }
__device__ __forceinline__ u16 f2bf(float f){
  unsigned u = __float_as_uint(f);
  u = (u + 0x7FFFu + ((u >> 16) & 1u)) >> 16;   // RNE
  return (u16)u;
}
__device__ __forceinline__ float bf2f(u16 u){ return __uint_as_float(((unsigned)u) << 16); }
__device__ __forceinline__ float bflo(u32 p){ return __uint_as_float(p << 16); }
__device__ __forceinline__ float bfhi(u32 p){ return __uint_as_float(p & 0xFFFF0000u); }
__device__ __forceinline__ u32 pack2(float a, float b){ return (u32)f2bf(a) | ((u32)f2bf(b)<<16); }

// ---------- CSR build ----------
__global__ void k_count(const int* __restrict__ edge_data, int* __restrict__ cnt){
  int e = blockIdx.x*blockDim.x + threadIdx.x;
  if(e < EF) atomicAdd(&cnt[edge_data[2*EF + e]], 1);
}

__global__ void k_scan(const int* __restrict__ cnt, int* __restrict__ row_start){
  __shared__ int wsum[16];
  __shared__ int s_run;
  int tid = threadIdx.x;          // 1024
  int lane = tid & 63, wv = tid >> 6;
  if(tid==0) s_run = 0;
  __syncthreads();
  const int CH = 4096;
  const int nch = (NE + CH - 1)/CH;  // 13
  for(int c=0;c<nch;c++){
    int base = c*CH + tid*4;
    int v0 = base   < NE ? cnt[base]   : 0;
    int v1 = base+1 < NE ? cnt[base+1] : 0;
    int v2 = base+2 < NE ? cnt[base+2] : 0;
    int v3 = base+3 < NE ? cnt[base+3] : 0;
    int tsum = v0+v1+v2+v3;
    int x = tsum;
    #pragma unroll
    for(int o=1;o<64;o<<=1){
      int y = __shfl_up(x, o);
      if(lane >= o) x += y;
    }
    if(lane==63) wsum[wv] = x;
    __syncthreads();
    if(wv==0 && lane<16){
      int w = wsum[lane];
      #pragma unroll
      for(int o=1;o<16;o<<=1){
        int y = __shfl_up(w, o);
        if(lane>=o) w += y;
      }
      wsum[lane] = w;
    }
    __syncthreads();
    int woff = (wv>0) ? wsum[wv-1] : 0;
    int excl = s_run + woff + x - tsum;
    if(base   < NE) row_start[base]   = excl;
    if(base+1 < NE) row_start[base+1] = excl + v0;
    if(base+2 < NE) row_start[base+2] = excl + v0+v1;
    if(base+3 < NE) row_start[base+3] = excl + v0+v1+v2;
    __syncthreads();
    if(tid==1023) s_run += wsum[15];
    __syncthreads();
  }
  if(tid==0) row_start[NE] = s_run;
}

__global__ void k_fill(const int* __restrict__ edge_data, const int* __restrict__ row_start,
                       int* __restrict__ cnt, int* __restrict__ src_s, int* __restrict__ rel_s){
  int e = blockIdx.x*blockDim.x + threadIdx.x;
  if(e < EF){
    int s = edge_data[e], r = edge_data[EF+e], d = edge_data[2*EF+e];
    int pos = row_start[d] + atomicAdd(&cnt[d], 1);
    src_s[pos] = s; rel_s[pos] = r;
  }
}

// ---------- folds: vecE (edge-att), vs/vd (W@att folds for src/dst dots) ----------
__global__ void k_fold(const float* __restrict__ We1, const float* __restrict__ ae1,
                       const float* __restrict__ We2, const float* __restrict__ ae2,
                       const float* __restrict__ W1,  const float* __restrict__ as1, const float* __restrict__ ad1,
                       const float* __restrict__ W2,  const float* __restrict__ as2, const float* __restrict__ ad2,
                       float* __restrict__ vecE1, float* __restrict__ vecE2,
                       float* __restrict__ vs1, float* __restrict__ vd1,
                       float* __restrict__ vs2, float* __restrict__ vd2){
  int t = threadIdx.x;           // 256
  int d = t>>1, h = t&1;
  float sE=0.f, sS=0.f, sD=0.f;
  for(int c=0;c<64;c++){
    float we = We1[d*128 + h*64 + c];
    float w  = W1 [d*128 + h*64 + c];
    sE += we*ae1[h*64+c]; sS += w*as1[h*64+c]; sD += w*ad1[h*64+c];
  }
  vecE1[d*2+h] = sE; vs1[h*128+d] = sS; vd1[h*128+d] = sD;
  sE=0.f; sS=0.f; sD=0.f;
  for(int c=0;c<128;c++){
    float we = We2[d*256 + h*128 + c];
    float w  = W2 [d*256 + h*128 + c];
    sE += we*ae2[h*128+c]; sS += w*as2[h*128+c]; sD += w*ad2[h*128+c];
  }
  vecE2[d*2+h] = sE; vs2[h*128+d] = sS; vd2[h*128+d] = sD;
}

__global__ void k_aE(const float* __restrict__ rel_emb, const float* __restrict__ vecE1,
                     const float* __restrict__ vecE2, float* __restrict__ aE1, float* __restrict__ aE2){
  int r = blockIdx.x, l = threadIdx.x;  // 64 threads
  float re0 = rel_emb[r*128 + l], re1 = rel_emb[r*128 + 64 + l];
  float a10 = re0*vecE1[l*2+0] + re1*vecE1[(64+l)*2+0];
  float a11 = re0*vecE1[l*2+1] + re1*vecE1[(64+l)*2+1];
  float a20 = re0*vecE2[l*2+0] + re1*vecE2[(64+l)*2+0];
  float a21 = re0*vecE2[l*2+1] + re1*vecE2[(64+l)*2+1];
  for(int o=32;o;o>>=1){
    a10 += __shfl_xor(a10,o); a11 += __shfl_xor(a11,o);
    a20 += __shfl_xor(a20,o); a21 += __shfl_xor(a21,o);
  }
  if(l==0){ aE1[r*2]=a10; aE1[r*2+1]=a11; aE2[r*2]=a20; aE2[r*2+1]=a21; }
}

__global__ void k_tr(const float* __restrict__ A, float* __restrict__ At, int R, int C){
  int t = blockIdx.x*blockDim.x + threadIdx.x;
  if(t < R*C){ int r = t / C, c = t % C; At[c*R + r] = A[t]; }
}

// ---------- build bf16 GEMM weight mats (WT layout: [out_col][k]) ----------
// WT1cat[128][256]: block-diag [W1_h0 | W1_h1];  WT2cat[128][256]: 0.5*[W2_h0 ; W2_h1] (head-mean fold)
// WTsk[128][128]: skip (ent @ W_skip^T -> WT[c][d] = W_skip[c][d]);  b2m = 0.5*(b2_h0+b2_h1)
__global__ void k_prep(const float* __restrict__ W1, const float* __restrict__ W2,
                       const float* __restrict__ Wsk, const float* __restrict__ b2,
                       u16* __restrict__ WT1, u16* __restrict__ WT2,
                       u16* __restrict__ WTs, float* __restrict__ b2m){
  int b = blockIdx.x, t = threadIdx.x;   // 385 x 128
  if(b < 128){
    int c = b;
    #pragma unroll
    for(int rr=0; rr<2; rr++){
      int r = rr*128 + t;
      float v;
      if(c < 64) v = (r < 128)  ? W1[r*128 + c] : 0.f;
      else       v = (r >= 128) ? W1[(r-128)*128 + c] : 0.f;
      WT1[c*256 + r] = f2bf(v);
    }
  } else if(b < 256){
    int c = b - 128;
    #pragma unroll
    for(int rr=0; rr<2; rr++){
      int r = rr*128 + t;
      float v = (r < 128) ? W2[r*256 + c] : W2[(r-128)*256 + 128 + c];
      WT2[c*256 + r] = f2bf(0.5f*v);
    }
  } else if(b < 384){
    int c = b - 256;
    WTs[c*128 + t] = f2bf(Wsk[c*128 + t]);
  } else {
    b2m[t] = 0.5f*(b2[t] + b2[128 + t]);
  }
}

// ---------- per-node: ent -> bf16 copy + layer-1 src/dst attention dots ----------
__global__ __launch_bounds__(256) void k_pre1(const float* __restrict__ ent, u16* __restrict__ entb,
                       float* __restrict__ asrc, float* __restrict__ adst,
                       const float* __restrict__ vs, const float* __restrict__ vd){
  __shared__ float s_vs[256], s_vd[256];
  int tid = threadIdx.x;
  s_vs[tid] = vs[tid]; s_vd[tid] = vd[tid];
  __syncthreads();
  int wv = tid>>6, l = tid&63;
  int n = blockIdx.x*4 + wv;
  if(n >= NE) return;
  float2 e2 = reinterpret_cast<const float2*>(ent)[(size_t)n*64 + l];
  reinterpret_cast<u32*>(entb)[(size_t)n*64 + l] = pack2(e2.x, e2.y);
  float s0 = e2.x*s_vs[2*l]     + e2.y*s_vs[2*l+1];
  float s1 = e2.x*s_vs[128+2*l] + e2.y*s_vs[128+2*l+1];
  float d0 = e2.x*s_vd[2*l]     + e2.y*s_vd[2*l+1];
  float d1 = e2.x*s_vd[128+2*l] + e2.y*s_vd[128+2*l+1];
  #pragma unroll
  for(int o=32;o;o>>=1){
    s0+=__shfl_xor(s0,o); s1+=__shfl_xor(s1,o);
    d0+=__shfl_xor(d0,o); d1+=__shfl_xor(d1,o);
  }
  if(l==0){ asrc[n*2]=s0; asrc[n*2+1]=s1; adst[n*2]=d0; adst[n*2+1]=d1; }
}

// ---------- per-node layer-2 dots from bf16 h1 ----------
__global__ __launch_bounds__(256) void k_dots2(const u16* __restrict__ h1,
                       float* __restrict__ asrc, float* __restrict__ adst,
                       const float* __restrict__ vs, const float* __restrict__ vd){
  __shared__ float s_vs[256], s_vd[256];
  int tid = threadIdx.x;
  s_vs[tid] = vs[tid]; s_vd[tid] = vd[tid];
  __syncthreads();
  int wv = tid>>6, l = tid&63;
  int n = blockIdx.x*4 + wv;
  if(n >= NE) return;
  u32 p = reinterpret_cast<const u32*>(h1)[(size_t)n*64 + l];
  float x0 = bflo(p), x1 = bfhi(p);
  float s0 = x0*s_vs[2*l]     + x1*s_vs[2*l+1];
  float s1 = x0*s_vs[128+2*l] + x1*s_vs[128+2*l+1];
  float d0 = x0*s_vd[2*l]     + x1*s_vd[2*l+1];
  float d1 = x0*s_vd[128+2*l] + x1*s_vd[128+2*l+1];
  #pragma unroll
  for(int o=32;o;o>>=1){
    s0+=__shfl_xor(s0,o); s1+=__shfl_xor(s1,o);
    d0+=__shfl_xor(d0,o); d1+=__shfl_xor(d1,o);
  }
  if(l==0){ asrc[n*2]=s0; asrc[n*2+1]=s1; adst[n*2]=d0; adst[n*2+1]=d1; }
}

// ---------- GAT aggregation on RAW features (pre-GEMM, by linearity) ----------
// tab: bf16 [N][128]; out aggE: bf16 [N][256] = [head0 conv | head1 conv], alpha-normalized.
// Direct exp (no max-sub): logits are O(0.1), mathematically identical after normalize.
__global__ __launch_bounds__(256) void k_agg(const u16* __restrict__ tab,
    const float* __restrict__ asrc, const float* __restrict__ adst,
    const float* __restrict__ aE, const int* __restrict__ row_start,
    const int* __restrict__ src_s, const int* __restrict__ rel_s,
    u16* __restrict__ aggE){
  __shared__ float2 sAE[NR];
  int tid = threadIdx.x;
  for(int i=tid; i<NR; i+=256) sAE[i] = reinterpret_cast<const float2*>(aE)[i];
  __syncthreads();
  int wv = tid>>6, l = tid&63;
  int n = blockIdx.x*4 + wv;
  if(n >= NE) return;
  int b = row_start[n], e = row_start[n+1];
  float2 ad  = reinterpret_cast<const float2*>(adst)[n];
  float2 asn = reinterpret_cast<const float2*>(asrc)[n];
  const u32* tu = reinterpret_cast<const u32*>(tab);
  float den0=0.f, den1=0.f, sE0=0.f, sE1=0.f;
  float a00=0.f, a01=0.f, a10=0.f, a11=0.f;
  for(int i=b;i<e;i++){
    int s = src_s[i], r = rel_s[i];
    float2 as = reinterpret_cast<const float2*>(asrc)[s];
    float2 ae = sAE[r];
    sE0 += ae.x; sE1 += ae.y;
    float l0 = lrelu(as.x + ad.x + ae.x);
    float l1 = lrelu(as.y + ad.y + ae.y);
    float w0 = __expf(l0), w1 = __expf(l1);
    den0 += w0; den1 += w1;
    u32 p = tu[(size_t)s*64 + l];
    float x0 = bflo(p), x1 = bfhi(p);
    a00 += w0*x0; a01 += w0*x1;
    a10 += w1*x0; a11 += w1*x1;
  }
  { // self-loop: edge_attr = mean of incoming aE (PyG fill_value='mean')
    float invdeg = 1.f/fmaxf((float)(e-b), 1.f);
    float l0 = lrelu(asn.x + ad.x + sE0*invdeg);
    float l1 = lrelu(asn.y + ad.y + sE1*invdeg);
    float w0 = __expf(l0), w1 = __expf(l1);
    den0 += w0; den1 += w1;
    u32 p = tu[(size_t)n*64 + l];
    float x0 = bflo(p), x1 = bfhi(p);
    a00 += w0*x0; a01 += w0*x1;
    a10 += w1*x0; a11 += w1*x1;
  }
  float i0 = 1.f/(den0 + 1e-16f), i1 = 1.f/(den1 + 1e-16f);
  u32* og = reinterpret_cast<u32*>(aggE);
  og[(size_t)n*128 + l]      = pack2(a00*i0, a01*i0);
  og[(size_t)n*128 + 64 + l] = pack2(a10*i1, a11*i1);
}

// ---------- MFMA GEMM: Y[N,128] = X[N,K] @ WT^T (WT[128][K] bf16) ----------
// EPI 0: plain bf16 out. EPI 1: +bias, lrelu, bf16 out. EPI 2: +bias +skip(bf16), row-L2-normalize, bf16 out.
template<int K, int EPI>
__global__ __launch_bounds__(256) void k_mgemm(const u16* __restrict__ X, const u16* __restrict__ WT,
    u16* __restrict__ Y, const float* __restrict__ bias, const u16* __restrict__ skip, int Nrows){
  constexpr int KC  = K/8;                 // 16B chunks per row
  constexpr int KSH = (K==256) ? 5 : 4;
  __shared__ u16 As[64*K];
  __shared__ u16 Bs[64*128];
  __shared__ float rsum[64][2];
  int n0 = blockIdx.x*64, t = threadIdx.x;
  // stage A once (swizzle: chunk kc stored at kc ^ (row&7))
  #pragma unroll
  for(int i=0;i<K/32;i++){
    int c = i*256 + t;
    int row = c >> KSH, kc = c & (KC-1);
    u16x8 pk = (u16x8)(u16)0;
    if(n0+row < Nrows) pk = *reinterpret_cast<const u16x8*>(&X[(size_t)(n0+row)*K + kc*8]);
    *reinterpret_cast<u16x8*>(&As[row*K + ((kc ^ (row&7))<<3)]) = pk;
  }
  int l = t&63, w = t>>6, wr = w>>1, wc = w&1, lr = l&15, kg = l>>4;
  const bf16x8* asp = reinterpret_cast<const bf16x8*>(As);
  const bf16x8* bsp = reinterpret_cast<const bf16x8*>(Bs);
  f32x4 acc[2][2][2] = {};   // [cbi][m][n]
  constexpr int NKH = K/128;
  for(int cbi=0;cbi<2;cbi++){
    for(int kh=0;kh<NKH;kh++){
      #pragma unroll
      for(int i=0;i<4;i++){
        int c = i*256 + t;
        int row = c>>4, kc = c&15;
        u16x8 pk = *reinterpret_cast<const u16x8*>(&WT[(size_t)(cbi*64+row)*K + kh*128 + kc*8]);
        *reinterpret_cast<u16x8*>(&Bs[row*128 + ((kc ^ (row&7))<<3)]) = pk;
      }
      __syncthreads();
      #pragma unroll
      for(int kk=0;kk<4;kk++){
        bf16x8 a[2], bb[2];
        #pragma unroll
        for(int m=0;m<2;m++){
          int fr = wr*32 + m*16 + lr;
          a[m] = asp[fr*(K/8) + ((kh*16 + kk*4 + kg) ^ (fr&7))];
        }
        #pragma unroll
        for(int nn=0;nn<2;nn++){
          int fc = wc*32 + nn*16 + lr;
          bb[nn] = bsp[fc*16 + ((kk*4 + kg) ^ (fc&7))];
        }
        #pragma unroll
        for(int m=0;m<2;m++)
          #pragma unroll
          for(int nn=0;nn<2;nn++)
            acc[cbi][m][nn] = __builtin_amdgcn_mfma_f32_16x16x32_bf16(a[m], bb[nn], acc[cbi][m][nn], 0, 0, 0);
      }
      __syncthreads();
    }
  }
  // epilogue: D lane map col=lr, row=kg*4+r (verified layout)
  if(EPI < 2){
    #pragma unroll
    for(int cbi=0;cbi<2;cbi++)
      #pragma unroll
      for(int m=0;m<2;m++)
        #pragma unroll
        for(int r=0;r<4;r++){
          int grow = n0 + wr*32 + m*16 + kg*4 + r;
          if(grow < Nrows){
            #pragma unroll
            for(int nn=0;nn<2;nn++){
              int gcol = cbi*64 + wc*32 + nn*16 + lr;
              float v = acc[cbi][m][nn][r];
              if(EPI==1){ v += bias[gcol]; v = lrelu(v); }
              Y[(size_t)grow*128 + gcol] = f2bf(v);
            }
          }
        }
  } else {
    // v = acc + bias + skip, then L2-normalize over the 128-wide row (cross-wave via LDS)
    #pragma unroll
    for(int cbi=0;cbi<2;cbi++)
      #pragma unroll
      for(int m=0;m<2;m++)
        #pragma unroll
        for(int r=0;r<4;r++){
          int grow = n0 + wr*32 + m*16 + kg*4 + r;
          if(grow < Nrows){
            #pragma unroll
            for(int nn=0;nn<2;nn++){
              int gcol = cbi*64 + wc*32 + nn*16 + lr;
              acc[cbi][m][nn][r] += bias[gcol] + bf2f(skip[(size_t)grow*128 + gcol]);
            }
          }
        }
    #pragma unroll
    for(int m=0;m<2;m++)
      #pragma unroll
      for(int r=0;r<4;r++){
        float s = 0.f;
        #pragma unroll
        for(int cbi=0;cbi<2;cbi++)
          #pragma unroll
          for(int nn=0;nn<2;nn++){ float v = acc[cbi][m][nn][r]; s += v*v; }
        #pragma unroll
        for(int o=1;o<16;o<<=1) s += __shfl_xor(s, o);   // reduce over lr within 16-lane group
        if(lr==0) rsum[wr*32 + m*16 + kg*4 + r][wc] = s;
      }
    __syncthreads();
    #pragma unroll
    for(int m=0;m<2;m++)
      #pragma unroll
      for(int r=0;r<4;r++){
        int row = wr*32 + m*16 + kg*4 + r;
        int grow = n0 + row;
        if(grow < Nrows){
          float tot = rsum[row][0] + rsum[row][1];
          float inv = 1.f/fmaxf(sqrtf(tot), 1e-12f);
          #pragma unroll
          for(int cbi=0;cbi<2;cbi++)
            #pragma unroll
            for(int nn=0;nn<2;nn++){
              int gcol = cbi*64 + wc*32 + nn*16 + lr;
              Y[(size_t)grow*128 + gcol] = f2bf(acc[cbi][m][nn][r]*inv);
            }
        }
      }
  }
}

__global__ void k_gather(const int* __restrict__ ei, const u16* __restrict__ xf,
                         float* __restrict__ out){
  int wv = threadIdx.x>>6, l = threadIdx.x&63;
  int e = blockIdx.x*4 + wv;
  if(e >= EB) return;
  int i0 = ei[e], i1 = ei[EB + e];
  u32 p0 = reinterpret_cast<const u32*>(xf)[(size_t)i0*64 + l];
  u32 p1 = reinterpret_cast<const u32*>(xf)[(size_t)i1*64 + l];
  reinterpret_cast<float2*>(out)[(size_t)e*64 + l] = make_float2(bflo(p0), bfhi(p0));
  reinterpret_cast<float2*>(out + (size_t)EB*128)[(size_t)e*64 + l] = make_float2(bflo(p1), bfhi(p1));
}

// ---------- edge_attr @ W_r.T via one-hot sparsity (exact f32) ----------
__global__ void k_attr(const float* __restrict__ ea, const float* __restrict__ Wrt,
                       float* __restrict__ out){
  int wv = threadIdx.x>>6, l = threadIdx.x&63;
  int e = blockIdx.x*4 + wv;
  if(e >= EB) return;
  const float* row = ea + (size_t)e*NR;
  float acc0=0.f, acc1=0.f;
  #pragma unroll
  for(int ch=0; ch<4; ch++){
    int idx = ch*64 + l;
    float v = (idx < NR) ? row[idx] : 0.f;
    unsigned long long mask = __ballot(v != 0.f);
    while(mask){
      int bit = __builtin_ctzll(mask);
      mask &= mask - 1;
      int r = ch*64 + bit;
      float vv = __shfl(v, bit);
      acc0 += vv * Wrt[r*128 + l];
      acc1 += vv * Wrt[r*128 + 64 + l];
    }
  }
  out[(size_t)e*128 + l]      = acc0;
  out[(size_t)e*128 + 64 + l] = acc1;
}

extern "C" void kernel_launch(void* const* d_in, const int* in_sizes, int n_in,
                              void* d_out, int out_size, void* d_ws, size_t ws_size,
                              hipStream_t stream){
  const int*   edge_index = (const int*)  d_in[0];
  const float* edge_attr  = (const float*)d_in[1];
  const int*   edge_data  = (const int*)  d_in[2];
  const float* ent_emb    = (const float*)d_in[3];
  const float* rel_emb    = (const float*)d_in[4];
  const float* W1     = (const float*)d_in[5];
  const float* We1    = (const float*)d_in[6];
  const float* att_s1 = (const float*)d_in[7];
  const float* att_d1 = (const float*)d_in[8];
  const float* att_e1 = (const float*)d_in[9];
  const float* b1     = (const float*)d_in[10];
  const float* W2     = (const float*)d_in[11];
  const float* We2    = (const float*)d_in[12];
  const float* att_s2 = (const float*)d_in[13];
  const float* att_d2 = (const float*)d_in[14];
  const float* att_e2 = (const float*)d_in[15];
  const float* b2     = (const float*)d_in[16];
  const float* W_skip = (const float*)d_in[17];
  const float* W_r    = (const float*)d_in[18];
  float* out = (float*)d_out;

  char* ws = (char*)d_ws;
  size_t off = 0;
  auto alloc = [&](size_t bytes){ void* p = ws + off; off += (bytes + 255) & ~(size_t)255; return p; };
  int*   cnt       = (int*)  alloc((size_t)NE*4);
  int*   row_start = (int*)  alloc((size_t)(NE+1)*4);
  int*   src_s     = (int*)  alloc((size_t)EF*4);
  int*   rel_s     = (int*)  alloc((size_t)EF*4);
  float* vecE1     = (float*)alloc(128*2*4);
  float* vecE2     = (float*)alloc(128*2*4);
  float* aE1       = (float*)alloc(NR*2*4);
  float* aE2       = (float*)alloc(NR*2*4);
  float* vs1       = (float*)alloc(256*4);
  float* vd1       = (float*)alloc(256*4);
  float* vs2       = (float*)alloc(256*4);
  float* vd2       = (float*)alloc(256*4);
  float* b2m       = (float*)alloc(128*4);
  float* asrc1     = (float*)alloc((size_t)NE*2*4);
  float* adst1     = (float*)alloc((size_t)NE*2*4);
  float* asrc2     = (float*)alloc((size_t)NE*2*4);
  float* adst2     = (float*)alloc((size_t)NE*2*4);
  u16*   WT1cat    = (u16*)  alloc(128*256*2);
  u16*   WT2cat    = (u16*)  alloc(128*256*2);
  u16*   WTsk      = (u16*)  alloc(128*128*2);
  float* Wrt       = (float*)alloc(NR*128*4);
  u16*   entb      = (u16*)  alloc((size_t)NE*128*2);   // bf16 ent; reused as xf
  u16*   h1        = (u16*)  alloc((size_t)NE*128*2);   // bf16
  u16*   skip      = (u16*)  alloc((size_t)NE*128*2);   // bf16
  u16*   xf = entb;   // entb dead after skip-gemm & agg1; mgemm_B writes xf here
  // d_out as scratch for aggE buffers (dead before k_gather/k_attr writes, stream-ordered)
  u16*   aggE1 = (u16*)out;                         // [NE][256] bf16 = 25.6 MB
  u16*   aggE2 = (u16*)out + (size_t)NE*256;        // next 25.6 MB

  hipMemsetAsync(cnt, 0, (size_t)NE*4, stream);
  k_count<<<(EF+255)/256, 256, 0, stream>>>(edge_data, cnt);
  k_scan<<<1, 1024, 0, stream>>>(cnt, row_start);
  hipMemsetAsync(cnt, 0, (size_t)NE*4, stream);
  k_fill<<<(EF+255)/256, 256, 0, stream>>>(edge_data, row_start, cnt, src_s, rel_s);

  k_fold<<<1, 256, 0, stream>>>(We1, att_e1, We2, att_e2, W1, att_s1, att_d1,
                                W2, att_s2, att_d2, vecE1, vecE2, vs1, vd1, vs2, vd2);
  k_aE<<<NR, 64, 0, stream>>>(rel_emb, vecE1, vecE2, aE1, aE2);
  k_prep<<<385, 128, 0, stream>>>(W1, W2, W_skip, b2, WT1cat, WT2cat, WTsk, b2m);
  k_tr<<<(128*NR+255)/256, 256, 0, stream>>>(W_r, Wrt, 128, NR);

  int gn = (NE+3)/4, gm = (NE+63)/64;
  k_pre1<<<gn, 256, 0, stream>>>(ent_emb, entb, asrc1, adst1, vs1, vd1);
  k_agg<<<gn, 256, 0, stream>>>(entb, asrc1, adst1, aE1, row_start, src_s, rel_s, aggE1);
  k_mgemm<256,1><<<gm, 256, 0, stream>>>(aggE1, WT1cat, h1, b1, nullptr, NE);
  k_dots2<<<gn, 256, 0, stream>>>(h1, asrc2, adst2, vs2, vd2);
  k_agg<<<gn, 256, 0, stream>>>(h1, asrc2, adst2, aE2, row_start, src_s, rel_s, aggE2);
  k_mgemm<128,0><<<gm, 256, 0, stream>>>(entb, WTsk, skip, nullptr, nullptr, NE);
  k_mgemm<256,2><<<gm, 256, 0, stream>>>(aggE2, WT2cat, xf, b2m, skip, NE);

  k_gather<<<(EB+3)/4, 256, 0, stream>>>(edge_index, xf, out);
  k_attr<<<(EB+3)/4, 256, 0, stream>>>(edge_attr, Wrt, out + (size_t)2*EB*128);
}

// Round 7
// 472.097 us; speedup vs baseline: 1.1218x; 1.1218x over previous
//
#include <hip/hip_runtime.h>

#define NE 50000      // N_ENT
#define NR 200        // N_REL
#define EF 300000     // E_FULL
#define EB 80000      // E_BATCH
#define NEG 0.2f

typedef unsigned short u16;
typedef unsigned int u32;
typedef u16 u16x8 __attribute__((ext_vector_type(8)));
typedef __bf16 bf16x8 __attribute__((ext_vector_type(8)));
typedef float f32x4 __attribute__((ext_vector_type(4)));

__device__ __forceinline__ float lrelu(float x){ return x >= 0.f ? x : NEG*x; }
__device__ __forceinline__ u16 f2bf(float f){
  unsigned u = __float_as_uint(f);
  u = (u + 0x7FFFu + ((u >> 16) & 1u)) >> 16;   // RNE
  return (u16)u;
}
__device__ __forceinline__ float bf2f(u16 u){ return __uint_as_float(((unsigned)u) << 16); }
__device__ __forceinline__ float bflo(u32 p){ return __uint_as_float(p << 16); }
__device__ __forceinline__ float bfhi(u32 p){ return __uint_as_float(p & 0xFFFF0000u); }
__device__ __forceinline__ u32 pack2(float a, float b){ return (u32)f2bf(a) | ((u32)f2bf(b)<<16); }

// ---------- CSR build ----------
__global__ void k_count(const int* __restrict__ edge_data, int* __restrict__ cnt){
  int e = blockIdx.x*blockDim.x + threadIdx.x;
  if(e < EF) atomicAdd(&cnt[edge_data[2*EF + e]], 1);
}

__global__ void k_scan(const int* __restrict__ cnt, int* __restrict__ row_start){
  __shared__ int wsum[16];
  __shared__ int s_run;
  int tid = threadIdx.x;          // 1024
  int lane = tid & 63, wv = tid >> 6;
  if(tid==0) s_run = 0;
  __syncthreads();
  const int CH = 4096;
  const int nch = (NE + CH - 1)/CH;  // 13
  for(int c=0;c<nch;c++){
    int base = c*CH + tid*4;
    int v0 = base   < NE ? cnt[base]   : 0;
    int v1 = base+1 < NE ? cnt[base+1] : 0;
    int v2 = base+2 < NE ? cnt[base+2] : 0;
    int v3 = base+3 < NE ? cnt[base+3] : 0;
    int tsum = v0+v1+v2+v3;
    int x = tsum;
    #pragma unroll
    for(int o=1;o<64;o<<=1){
      int y = __shfl_up(x, o);
      if(lane >= o) x += y;
    }
    if(lane==63) wsum[wv] = x;
    __syncthreads();
    if(wv==0 && lane<16){
      int w = wsum[lane];
      #pragma unroll
      for(int o=1;o<16;o<<=1){
        int y = __shfl_up(w, o);
        if(lane>=o) w += y;
      }
      wsum[lane] = w;
    }
    __syncthreads();
    int woff = (wv>0) ? wsum[wv-1] : 0;
    int excl = s_run + woff + x - tsum;
    if(base   < NE) row_start[base]   = excl;
    if(base+1 < NE) row_start[base+1] = excl + v0;
    if(base+2 < NE) row_start[base+2] = excl + v0+v1;
    if(base+3 < NE) row_start[base+3] = excl + v0+v1+v2;
    __syncthreads();
    if(tid==1023) s_run += wsum[15];
    __syncthreads();
  }
  if(tid==0) row_start[NE] = s_run;
}

// packed (src | rel<<16) CSR payload
__global__ void k_fill(const int* __restrict__ edge_data, const int* __restrict__ row_start,
                       int* __restrict__ cnt, u32* __restrict__ sr){
  int e = blockIdx.x*blockDim.x + threadIdx.x;
  if(e < EF){
    int s = edge_data[e], r = edge_data[EF+e], d = edge_data[2*EF+e];
    int pos = row_start[d] + atomicAdd(&cnt[d], 1);
    sr[pos] = (u32)s | ((u32)r << 16);
  }
}

// ---------- folds: vecE (edge-att), vs/vd (W@att folds) ----------
__global__ void k_fold(const float* __restrict__ We1, const float* __restrict__ ae1,
                       const float* __restrict__ We2, const float* __restrict__ ae2,
                       const float* __restrict__ W1,  const float* __restrict__ as1, const float* __restrict__ ad1,
                       const float* __restrict__ W2,  const float* __restrict__ as2, const float* __restrict__ ad2,
                       float* __restrict__ vecE1, float* __restrict__ vecE2,
                       float* __restrict__ vs1, float* __restrict__ vd1,
                       float* __restrict__ vs2, float* __restrict__ vd2){
  int t = threadIdx.x;           // 256
  int d = t>>1, h = t&1;
  float sE=0.f, sS=0.f, sD=0.f;
  for(int c=0;c<64;c++){
    float we = We1[d*128 + h*64 + c];
    float w  = W1 [d*128 + h*64 + c];
    sE += we*ae1[h*64+c]; sS += w*as1[h*64+c]; sD += w*ad1[h*64+c];
  }
  vecE1[d*2+h] = sE; vs1[h*128+d] = sS; vd1[h*128+d] = sD;
  sE=0.f; sS=0.f; sD=0.f;
  for(int c=0;c<128;c++){
    float we = We2[d*256 + h*128 + c];
    float w  = W2 [d*256 + h*128 + c];
    sE += we*ae2[h*128+c]; sS += w*as2[h*128+c]; sD += w*ad2[h*128+c];
  }
  vecE2[d*2+h] = sE; vs2[h*128+d] = sS; vd2[h*128+d] = sD;
}

__global__ void k_aE(const float* __restrict__ rel_emb, const float* __restrict__ vecE1,
                     const float* __restrict__ vecE2, float* __restrict__ aE1, float* __restrict__ aE2){
  int r = blockIdx.x, l = threadIdx.x;  // 64 threads
  float re0 = rel_emb[r*128 + l], re1 = rel_emb[r*128 + 64 + l];
  float a10 = re0*vecE1[l*2+0] + re1*vecE1[(64+l)*2+0];
  float a11 = re0*vecE1[l*2+1] + re1*vecE1[(64+l)*2+1];
  float a20 = re0*vecE2[l*2+0] + re1*vecE2[(64+l)*2+0];
  float a21 = re0*vecE2[l*2+1] + re1*vecE2[(64+l)*2+1];
  for(int o=32;o;o>>=1){
    a10 += __shfl_xor(a10,o); a11 += __shfl_xor(a11,o);
    a20 += __shfl_xor(a20,o); a21 += __shfl_xor(a21,o);
  }
  if(l==0){ aE1[r*2]=a10; aE1[r*2+1]=a11; aE2[r*2]=a20; aE2[r*2+1]=a21; }
}

// ---------- weight prep ----------
// WT1cat[128][256] block-diag W1; WT2cat[128][384] = [0.5*W2_h0 ; 0.5*W2_h1 ; W_skip];
// Wrt[200][128] = W_r^T; b2m = 0.5*(b2_h0 + b2_h1)
__global__ void k_prep(const float* __restrict__ W1, const float* __restrict__ W2,
                       const float* __restrict__ Wsk, const float* __restrict__ b2,
                       const float* __restrict__ W_r,
                       u16* __restrict__ WT1, u16* __restrict__ WT2,
                       float* __restrict__ Wrt, float* __restrict__ b2m){
  int b = blockIdx.x, t = threadIdx.x;   // 457 x 128
  if(b < 128){
    int c = b;
    #pragma unroll
    for(int rr=0; rr<2; rr++){
      int r = rr*128 + t;
      float v;
      if(c < 64) v = (r < 128)  ? W1[r*128 + c] : 0.f;
      else       v = (r >= 128) ? W1[(r-128)*128 + c] : 0.f;
      WT1[c*256 + r] = f2bf(v);
    }
  } else if(b < 256){
    int c = b - 128;
    #pragma unroll
    for(int rr=0; rr<2; rr++){
      int r = rr*128 + t;
      float v = (r < 128) ? W2[r*256 + c] : W2[(r-128)*256 + 128 + c];
      WT2[c*384 + r] = f2bf(0.5f*v);
    }
    WT2[c*384 + 256 + t] = f2bf(Wsk[c*128 + t]);   // skip fold (K segment 2)
  } else if(b < 456){
    int c = b - 256;   // relation
    Wrt[c*128 + t] = W_r[t*200 + c];
  } else {
    b2m[t] = 0.5f*(b2[t] + b2[128 + t]);
  }
}

// ---------- per-node: ent -> bf16 copy + layer-1 attention dots ----------
__global__ __launch_bounds__(256) void k_pre1(const float* __restrict__ ent, u16* __restrict__ entb,
                       float* __restrict__ asrc, float* __restrict__ adst,
                       const float* __restrict__ vs, const float* __restrict__ vd){
  __shared__ float s_vs[256], s_vd[256];
  int tid = threadIdx.x;
  s_vs[tid] = vs[tid]; s_vd[tid] = vd[tid];
  __syncthreads();
  int wv = tid>>6, l = tid&63;
  int n = blockIdx.x*4 + wv;
  if(n >= NE) return;
  float2 e2 = reinterpret_cast<const float2*>(ent)[(size_t)n*64 + l];
  reinterpret_cast<u32*>(entb)[(size_t)n*64 + l] = pack2(e2.x, e2.y);
  float s0 = e2.x*s_vs[2*l]     + e2.y*s_vs[2*l+1];
  float s1 = e2.x*s_vs[128+2*l] + e2.y*s_vs[128+2*l+1];
  float d0 = e2.x*s_vd[2*l]     + e2.y*s_vd[2*l+1];
  float d1 = e2.x*s_vd[128+2*l] + e2.y*s_vd[128+2*l+1];
  #pragma unroll
  for(int o=32;o;o>>=1){
    s0+=__shfl_xor(s0,o); s1+=__shfl_xor(s1,o);
    d0+=__shfl_xor(d0,o); d1+=__shfl_xor(d1,o);
  }
  if(l==0){ asrc[n*2]=s0; asrc[n*2+1]=s1; adst[n*2]=d0; adst[n*2+1]=d1; }
}

// ---------- GAT aggregation on raw features (pre-GEMM by linearity), 2x unrolled ----------
__global__ __launch_bounds__(256) void k_agg(const u16* __restrict__ tab,
    const float* __restrict__ asrc, const float* __restrict__ adst,
    const float* __restrict__ aE, const int* __restrict__ row_start,
    const u32* __restrict__ sr, u16* __restrict__ aggE){
  __shared__ float2 sAE[NR];
  int tid = threadIdx.x;
  for(int i=tid; i<NR; i+=256) sAE[i] = reinterpret_cast<const float2*>(aE)[i];
  __syncthreads();
  int wv = tid>>6, l = tid&63;
  int n = blockIdx.x*4 + wv;
  if(n >= NE) return;
  int b = row_start[n], e = row_start[n+1];
  float2 ad  = reinterpret_cast<const float2*>(adst)[n];
  float2 asn = reinterpret_cast<const float2*>(asrc)[n];
  const u32* tu = reinterpret_cast<const u32*>(tab);
  const float2* asp = reinterpret_cast<const float2*>(asrc);
  float den0=0.f, den1=0.f, sE0=0.f, sE1=0.f;
  float a00A=0.f, a01A=0.f, a10A=0.f, a11A=0.f;
  float a00B=0.f, a01B=0.f, a10B=0.f, a11B=0.f;
  int i = b;
  for(; i+2<=e; i+=2){
    u32 q0 = sr[i], q1 = sr[i+1];
    int s0i = q0 & 0xFFFF, r0 = q0 >> 16;
    int s1i = q1 & 0xFFFF, r1 = q1 >> 16;
    u32 p0 = tu[(size_t)s0i*64 + l];
    u32 p1 = tu[(size_t)s1i*64 + l];
    float2 as0 = asp[s0i], as1 = asp[s1i];
    float2 ae0 = sAE[r0],  ae1 = sAE[r1];
    sE0 += ae0.x + ae1.x; sE1 += ae0.y + ae1.y;
    float l00 = lrelu(as0.x + ad.x + ae0.x), l01 = lrelu(as0.y + ad.y + ae0.y);
    float l10 = lrelu(as1.x + ad.x + ae1.x), l11 = lrelu(as1.y + ad.y + ae1.y);
    float w00 = __expf(l00), w01 = __expf(l01);
    float w10 = __expf(l10), w11 = __expf(l11);
    den0 += w00 + w10; den1 += w01 + w11;
    float x00 = bflo(p0), x01 = bfhi(p0), x10 = bflo(p1), x11 = bfhi(p1);
    a00A += w00*x00; a01A += w00*x01; a10A += w01*x00; a11A += w01*x01;
    a00B += w10*x10; a01B += w10*x11; a10B += w11*x10; a11B += w11*x11;
  }
  if(i < e){
    u32 q0 = sr[i];
    int s0i = q0 & 0xFFFF, r0 = q0 >> 16;
    u32 p0 = tu[(size_t)s0i*64 + l];
    float2 as0 = asp[s0i];
    float2 ae0 = sAE[r0];
    sE0 += ae0.x; sE1 += ae0.y;
    float l00 = lrelu(as0.x + ad.x + ae0.x), l01 = lrelu(as0.y + ad.y + ae0.y);
    float w00 = __expf(l00), w01 = __expf(l01);
    den0 += w00; den1 += w01;
    float x00 = bflo(p0), x01 = bfhi(p0);
    a00A += w00*x00; a01A += w00*x01; a10A += w01*x00; a11A += w01*x01;
  }
  float a00 = a00A+a00B, a01 = a01A+a01B, a10 = a10A+a10B, a11 = a11A+a11B;
  { // self-loop: edge_attr = mean of incoming aE (PyG fill_value='mean')
    float invdeg = 1.f/fmaxf((float)(e-b), 1.f);
    float l0 = lrelu(asn.x + ad.x + sE0*invdeg);
    float l1 = lrelu(asn.y + ad.y + sE1*invdeg);
    float w0 = __expf(l0), w1 = __expf(l1);
    den0 += w0; den1 += w1;
    u32 p = tu[(size_t)n*64 + l];
    float x0 = bflo(p), x1 = bfhi(p);
    a00 += w0*x0; a01 += w0*x1;
    a10 += w1*x0; a11 += w1*x1;
  }
  float i0 = 1.f/(den0 + 1e-16f), i1 = 1.f/(den1 + 1e-16f);
  u32* og = reinterpret_cast<u32*>(aggE);
  og[(size_t)n*128 + l]      = pack2(a00*i0, a01*i0);
  og[(size_t)n*128 + 64 + l] = pack2(a10*i1, a11*i1);
}

// ---------- MFMA GEMM: Y[N,128] = [X | X2] @ WT^T (WT[128][K] bf16) ----------
// X stride 256 (u16), X2 stride 128 (K=384 only).
// EPI 1: +bias, lrelu, bf16 out, + per-row attention dots (vs,vd) -> asrc/adst.
// EPI 2: +bias, row-L2-normalize, bf16 out.
template<int K, int EPI>
__global__ __launch_bounds__(256) void k_mgemm(const u16* __restrict__ X, const u16* __restrict__ X2,
    const u16* __restrict__ WT, u16* __restrict__ Y, const float* __restrict__ bias,
    const float* __restrict__ vs, const float* __restrict__ vd,
    float* __restrict__ asrc, float* __restrict__ adst, int Nrows){
  constexpr int KC = K/8;                 // 16B chunks per row (32 or 48)
  __shared__ u16 As[64*K];
  __shared__ u16 Bs[64*128];
  __shared__ float red[64][8];            // EPI1: dots partials; EPI2: [row][wc] sqsum (uses [64][2])
  __shared__ float s_vs[256], s_vd[256];
  int n0 = blockIdx.x*64, t = threadIdx.x;
  if(EPI==1){ s_vs[t] = vs[t]; s_vd[t] = vd[t]; }
  // ---- stage A once ----
  #pragma unroll
  for(int i=0;i<KC/4;i++){
    int c = i*256 + t;
    int row = c / KC, kc = c % KC;
    u16x8 pk = (u16x8)(u16)0;
    if(n0+row < Nrows){
      if(K==256 || kc < 32) pk = *reinterpret_cast<const u16x8*>(&X [(size_t)(n0+row)*256 + kc*8]);
      else                  pk = *reinterpret_cast<const u16x8*>(&X2[(size_t)(n0+row)*128 + (kc-32)*8]);
    }
    *reinterpret_cast<u16x8*>(&As[row*K + ((kc ^ (row&7))<<3)]) = pk;
  }
  int l = t&63, w = t>>6, wr = w>>1, wc = w&1, lr = l&15, kg = l>>4;
  const bf16x8* asp = reinterpret_cast<const bf16x8*>(As);
  const bf16x8* bsp = reinterpret_cast<const bf16x8*>(Bs);
  f32x4 acc[2][2][2] = {};   // [cbi][m][nn]
  constexpr int NKH = K/128;
  for(int cbi=0;cbi<2;cbi++){
    for(int kh=0;kh<NKH;kh++){
      #pragma unroll
      for(int i=0;i<4;i++){
        int c = i*256 + t;
        int row = c>>4, kc = c&15;
        u16x8 pk = *reinterpret_cast<const u16x8*>(&WT[(size_t)(cbi*64+row)*K + kh*128 + kc*8]);
        *reinterpret_cast<u16x8*>(&Bs[row*128 + ((kc ^ (row&7))<<3)]) = pk;
      }
      __syncthreads();
      #pragma unroll
      for(int kk=0;kk<4;kk++){
        bf16x8 a[2], bb[2];
        #pragma unroll
        for(int m=0;m<2;m++){
          int fr = wr*32 + m*16 + lr;
          a[m] = asp[fr*KC + ((kh*16 + kk*4 + kg) ^ (fr&7))];
        }
        #pragma unroll
        for(int nn=0;nn<2;nn++){
          int fc = wc*32 + nn*16 + lr;
          bb[nn] = bsp[fc*16 + ((kk*4 + kg) ^ (fc&7))];
        }
        #pragma unroll
        for(int m=0;m<2;m++)
          #pragma unroll
          for(int nn=0;nn<2;nn++)
            acc[cbi][m][nn] = __builtin_amdgcn_mfma_f32_16x16x32_bf16(a[m], bb[nn], acc[cbi][m][nn], 0, 0, 0);
      }
      __syncthreads();
    }
  }
  // ---- epilogue: D lane map col=lr, row=kg*4+r ----
  if(EPI==1){
    #pragma unroll
    for(int cbi=0;cbi<2;cbi++)
      #pragma unroll
      for(int m=0;m<2;m++)
        #pragma unroll
        for(int r=0;r<4;r++){
          int grow = n0 + wr*32 + m*16 + kg*4 + r;
          #pragma unroll
          for(int nn=0;nn<2;nn++){
            int gcol = cbi*64 + wc*32 + nn*16 + lr;
            float v = lrelu(acc[cbi][m][nn][r] + bias[gcol]);
            acc[cbi][m][nn][r] = v;
            if(grow < Nrows) Y[(size_t)grow*128 + gcol] = f2bf(v);
          }
        }
    // per-row dots on post-activation h1
    #pragma unroll
    for(int m=0;m<2;m++)
      #pragma unroll
      for(int r=0;r<4;r++){
        float s0=0.f,s1=0.f,d0=0.f,d1=0.f;
        #pragma unroll
        for(int cbi=0;cbi<2;cbi++)
          #pragma unroll
          for(int nn=0;nn<2;nn++){
            int gcol = cbi*64 + wc*32 + nn*16 + lr;
            float v = acc[cbi][m][nn][r];
            s0 += v*s_vs[gcol]; s1 += v*s_vs[128+gcol];
            d0 += v*s_vd[gcol]; d1 += v*s_vd[128+gcol];
          }
        #pragma unroll
        for(int o=1;o<16;o<<=1){
          s0 += __shfl_xor(s0,o); s1 += __shfl_xor(s1,o);
          d0 += __shfl_xor(d0,o); d1 += __shfl_xor(d1,o);
        }
        if(lr==0){
          int row = wr*32 + m*16 + kg*4 + r;
          red[row][wc*4+0]=s0; red[row][wc*4+1]=s1;
          red[row][wc*4+2]=d0; red[row][wc*4+3]=d1;
        }
      }
    __syncthreads();
    if(t < 64){
      int grow = n0 + t;
      if(grow < Nrows){
        asrc[grow*2]   = red[t][0] + red[t][4];
        asrc[grow*2+1] = red[t][1] + red[t][5];
        adst[grow*2]   = red[t][2] + red[t][6];
        adst[grow*2+1] = red[t][3] + red[t][7];
      }
    }
  } else {
    #pragma unroll
    for(int cbi=0;cbi<2;cbi++)
      #pragma unroll
      for(int m=0;m<2;m++)
        #pragma unroll
        for(int r=0;r<4;r++)
          #pragma unroll
          for(int nn=0;nn<2;nn++){
            int gcol = cbi*64 + wc*32 + nn*16 + lr;
            acc[cbi][m][nn][r] += bias[gcol];
          }
    #pragma unroll
    for(int m=0;m<2;m++)
      #pragma unroll
      for(int r=0;r<4;r++){
        float s = 0.f;
        #pragma unroll
        for(int cbi=0;cbi<2;cbi++)
          #pragma unroll
          for(int nn=0;nn<2;nn++){ float v = acc[cbi][m][nn][r]; s += v*v; }
        #pragma unroll
        for(int o=1;o<16;o<<=1) s += __shfl_xor(s, o);
        if(lr==0) red[wr*32 + m*16 + kg*4 + r][wc] = s;
      }
    __syncthreads();
    #pragma unroll
    for(int m=0;m<2;m++)
      #pragma unroll
      for(int r=0;r<4;r++){
        int row = wr*32 + m*16 + kg*4 + r;
        int grow = n0 + row;
        if(grow < Nrows){
          float tot = red[row][0] + red[row][1];
          float inv = 1.f/fmaxf(sqrtf(tot), 1e-12f);
          #pragma unroll
          for(int cbi=0;cbi<2;cbi++)
            #pragma unroll
            for(int nn=0;nn<2;nn++){
              int gcol = cbi*64 + wc*32 + nn*16 + lr;
              Y[(size_t)grow*128 + gcol] = f2bf(acc[cbi][m][nn][r]*inv);
            }
        }
      }
  }
}

__global__ void k_gather(const int* __restrict__ ei, const u16* __restrict__ xf,
                         float* __restrict__ out){
  int wv = threadIdx.x>>6, l = threadIdx.x&63;
  int e = blockIdx.x*4 + wv;
  if(e >= EB) return;
  int i0 = ei[e], i1 = ei[EB + e];
  u32 p0 = reinterpret_cast<const u32*>(xf)[(size_t)i0*64 + l];
  u32 p1 = reinterpret_cast<const u32*>(xf)[(size_t)i1*64 + l];
  reinterpret_cast<float2*>(out)[(size_t)e*64 + l] = make_float2(bflo(p0), bfhi(p0));
  reinterpret_cast<float2*>(out + (size_t)EB*128)[(size_t)e*64 + l] = make_float2(bflo(p1), bfhi(p1));
}

// ---------- edge_attr @ W_r.T via one-hot sparsity, early-exit (exact f32) ----------
__global__ void k_attr(const float* __restrict__ ea, const float* __restrict__ Wrt,
                       float* __restrict__ out){
  int wv = threadIdx.x>>6, l = threadIdx.x&63;
  int e = blockIdx.x*4 + wv;
  if(e >= EB) return;
  const float* row = ea + (size_t)e*NR;
  float vv = 0.f; int rsel = 0;
  #pragma unroll
  for(int ch=0; ch<4; ch++){
    int idx = ch*64 + l;
    float v = (idx < NR) ? row[idx] : 0.f;
    unsigned long long mask = __ballot(v != 0.f);
    if(mask){
      int bit = __builtin_ctzll(mask);
      rsel = ch*64 + bit;
      vv = __shfl(v, bit);
      break;                       // one-hot: wave-uniform exit
    }
  }
  out[(size_t)e*128 + l]      = vv * Wrt[rsel*128 + l];
  out[(size_t)e*128 + 64 + l] = vv * Wrt[rsel*128 + 64 + l];
}

extern "C" void kernel_launch(void* const* d_in, const int* in_sizes, int n_in,
                              void* d_out, int out_size, void* d_ws, size_t ws_size,
                              hipStream_t stream){
  const int*   edge_index = (const int*)  d_in[0];
  const float* edge_attr  = (const float*)d_in[1];
  const int*   edge_data  = (const int*)  d_in[2];
  const float* ent_emb    = (const float*)d_in[3];
  const float* rel_emb    = (const float*)d_in[4];
  const float* W1     = (const float*)d_in[5];
  const float* We1    = (const float*)d_in[6];
  const float* att_s1 = (const float*)d_in[7];
  const float* att_d1 = (const float*)d_in[8];
  const float* att_e1 = (const float*)d_in[9];
  const float* b1     = (const float*)d_in[10];
  const float* W2     = (const float*)d_in[11];
  const float* We2    = (const float*)d_in[12];
  const float* att_s2 = (const float*)d_in[13];
  const float* att_d2 = (const float*)d_in[14];
  const float* att_e2 = (const float*)d_in[15];
  const float* b2     = (const float*)d_in[16];
  const float* W_skip = (const float*)d_in[17];
  const float* W_r    = (const float*)d_in[18];
  float* out = (float*)d_out;

  char* ws = (char*)d_ws;
  size_t off = 0;
  auto alloc = [&](size_t bytes){ void* p = ws + off; off += (bytes + 255) & ~(size_t)255; return p; };
  int*   cnt       = (int*)  alloc((size_t)NE*4);
  int*   row_start = (int*)  alloc((size_t)(NE+1)*4);
  u32*   sr        = (u32*)  alloc((size_t)EF*4);
  float* vecE1     = (float*)alloc(128*2*4);
  float* vecE2     = (float*)alloc(128*2*4);
  float* aE1       = (float*)alloc(NR*2*4);
  float* aE2       = (float*)alloc(NR*2*4);
  float* vs1       = (float*)alloc(256*4);
  float* vd1       = (float*)alloc(256*4);
  float* vs2       = (float*)alloc(256*4);
  float* vd2       = (float*)alloc(256*4);
  float* b2m       = (float*)alloc(128*4);
  float* asrc1     = (float*)alloc((size_t)NE*2*4);
  float* adst1     = (float*)alloc((size_t)NE*2*4);
  float* asrc2     = (float*)alloc((size_t)NE*2*4);
  float* adst2     = (float*)alloc((size_t)NE*2*4);
  u16*   WT1cat    = (u16*)  alloc(128*256*2);
  u16*   WT2cat    = (u16*)  alloc(128*384*2);
  float* Wrt       = (float*)alloc(NR*128*4);
  u16*   entb      = (u16*)  alloc((size_t)NE*128*2);   // bf16 ent; xf aliases (safe: per-block row ownership)
  u16*   h1        = (u16*)  alloc((size_t)NE*128*2);   // bf16
  u16*   xf = entb;
  // d_out as scratch for aggE buffers (dead before k_gather/k_attr writes, stream-ordered)
  u16*   aggE1 = (u16*)out;                         // [NE][256] bf16 = 25.6 MB
  u16*   aggE2 = (u16*)out + (size_t)NE*256;        // next 25.6 MB

  hipMemsetAsync(cnt, 0, (size_t)NE*4, stream);
  k_count<<<(EF+255)/256, 256, 0, stream>>>(edge_data, cnt);
  k_scan<<<1, 1024, 0, stream>>>(cnt, row_start);
  hipMemsetAsync(cnt, 0, (size_t)NE*4, stream);
  k_fill<<<(EF+255)/256, 256, 0, stream>>>(edge_data, row_start, cnt, sr);

  k_fold<<<1, 256, 0, stream>>>(We1, att_e1, We2, att_e2, W1, att_s1, att_d1,
                                W2, att_s2, att_d2, vecE1, vecE2, vs1, vd1, vs2, vd2);
  k_aE<<<NR, 64, 0, stream>>>(rel_emb, vecE1, vecE2, aE1, aE2);
  k_prep<<<457, 128, 0, stream>>>(W1, W2, W_skip, b2, W_r, WT1cat, WT2cat, Wrt, b2m);

  int gn = (NE+3)/4, gm = (NE+63)/64;
  k_pre1<<<gn, 256, 0, stream>>>(ent_emb, entb, asrc1, adst1, vs1, vd1);
  k_agg<<<gn, 256, 0, stream>>>(entb, asrc1, adst1, aE1, row_start, sr, aggE1);
  k_mgemm<256,1><<<gm, 256, 0, stream>>>(aggE1, nullptr, WT1cat, h1, b1, vs2, vd2, asrc2, adst2, NE);
  k_agg<<<gn, 256, 0, stream>>>(h1, asrc2, adst2, aE2, row_start, sr, aggE2);
  k_mgemm<384,2><<<gm, 256, 0, stream>>>(aggE2, entb, WT2cat, xf, b2m, nullptr, nullptr, nullptr, nullptr, NE);

  k_gather<<<(EB+3)/4, 256, 0, stream>>>(edge_index, xf, out);
  k_attr<<<(EB+3)/4, 256, 0, stream>>>(edge_attr, Wrt, out + (size_t)2*EB*128);
}